// Round 4
// baseline (137.731 us; speedup 1.0000x reference)
//
#include <hip/hip_runtime.h>
#include <hip/hip_bf16.h>

#define BS 4
#define NF 8
#define NT 256
#define DIN 64
#define NH 8
#define DOUT 64
#define TT 8          // t's per attn block
#define MROWS 64      // TT*NH score rows per block
#define NCHUNK 32     // NT/TT

typedef unsigned short u16;
typedef __attribute__((ext_vector_type(8))) short short8;
typedef __attribute__((ext_vector_type(4))) float f32x4;
typedef __attribute__((ext_vector_type(4))) unsigned int u32x4;

static __device__ __forceinline__ u16 f2bf(float x) {
    __hip_bfloat16 h = __float2bfloat16(x);
    u16 r; __builtin_memcpy(&r, &h, 2); return r;
}
static __device__ __forceinline__ unsigned pk2(float a, float b) {
    return (unsigned)f2bf(a) | ((unsigned)f2bf(b) << 16);
}

// ---------------------------------------------------------------------------
// prep: [0,2048) qk projections (LDS-free, shuffle-reduced)
//       [2048,2080) X -> XT bf16 [bf][d][l] ; [2080,2144) W -> Wt bf16 [f][o][kk]
// ---------------------------------------------------------------------------
__global__ __launch_bounds__(256) void prep_kernel(
    const float* __restrict__ X,
    const float* __restrict__ Wq,
    const float* __restrict__ Wk,
    const float* __restrict__ W,
    float* __restrict__ q,
    float* __restrict__ k,
    u16* __restrict__ XT,
    u16* __restrict__ Wt)
{
    __shared__ float sT[64][65];
    const int tid = threadIdx.x;
    const int bid = blockIdx.x;

    if (bid < 2048) {
        // ---- qk projection, one (f,t) per block, no LDS ----
        const int ft = bid;                  // f*NT + t
        const int f = ft >> 8, t = ft & 255;
        const int dsp   = tid & 7;           // d-split: 8 d's each
        const int heq   = (tid >> 3) & 3;    // he quad
        const int b     = (tid >> 5) & 3;
        const int which = tid >> 7;

        // X[b,f,t, dsp*8 .. dsp*8+7]
        const float* xp = X + (((size_t)((b * NF + f) * NT + t)) << 6) + (dsp << 3);
        float4 x0 = *(const float4*)xp;
        float4 x1 = *(const float4*)(xp + 4);

        // W[f,t, d, heq*4 .. +3], d = dsp*8 + j
        const float* wmat = which ? Wk : Wq;
        const float* wp = wmat + ((size_t)ft << 10) + ((dsp << 3) << 4) + (heq << 2);

        float4 a = {0.f, 0.f, 0.f, 0.f};
        float xs[8] = {x0.x, x0.y, x0.z, x0.w, x1.x, x1.y, x1.z, x1.w};
        #pragma unroll
        for (int j = 0; j < 8; ++j) {
            float4 w4 = *(const float4*)(wp + (j << 4));
            a.x = fmaf(xs[j], w4.x, a.x);
            a.y = fmaf(xs[j], w4.y, a.y);
            a.z = fmaf(xs[j], w4.z, a.z);
            a.w = fmaf(xs[j], w4.w, a.w);
        }
        // butterfly reduce over dsp (lane bits 0-2)
        #pragma unroll
        for (int off = 1; off < 8; off <<= 1) {
            a.x += __shfl_xor(a.x, off);
            a.y += __shfl_xor(a.y, off);
            a.z += __shfl_xor(a.z, off);
            a.w += __shfl_xor(a.w, off);
        }
        if (dsp == 0) {
            float* outp = which ? k : q;
            *(float4*)(outp + (((size_t)((b * NF + f) * NT + t)) << 4) + (heq << 2)) = a;
        }
    } else if (bid < 2080) {
        const int bf = bid - 2048;
        for (int lc = 0; lc < 4; ++lc) {
            #pragma unroll
            for (int i = 0; i < 16; ++i) {
                int l = i * 4 + (tid >> 6), d = tid & 63;
                sT[l][d] = X[(((size_t)(bf * NT) + lc * 64 + l) << 6) + d];
            }
            __syncthreads();
            #pragma unroll
            for (int i = 0; i < 16; ++i) {
                int d = i * 4 + (tid >> 6), l = tid & 63;
                XT[(((size_t)(bf * 64) + d) << 8) + lc * 64 + l] = f2bf(sT[l][d]);
            }
            __syncthreads();
        }
    } else {
        const int idx = bid - 2080;
        const int f = idx >> 3, kc = idx & 7;
        #pragma unroll
        for (int i = 0; i < 16; ++i) {
            int kk = i * 4 + (tid >> 6), o = tid & 63;
            sT[kk][o] = W[(((size_t)(f * 512) + kc * 64 + kk) << 6) + o];
        }
        __syncthreads();
        #pragma unroll
        for (int i = 0; i < 16; ++i) {
            int o = i * 4 + (tid >> 6), kk = tid & 63;
            Wt[(((size_t)(f * 64) + o) << 9) + kc * 64 + kk] = f2bf(sT[kk][o]);
        }
    }
}

// ---------------------------------------------------------------------------
// attn: block = (b, f, 8-t chunk). Scores fp32 VALU (2-pass softmax) ->
// P bf16 in LDS (swizzled A-layout) -> MFMA P@X -> MFMA vals@W -> out.
// (UNCHANGED from round 3 for clean attribution.)
// ---------------------------------------------------------------------------
__global__ __launch_bounds__(256, 2) void attn_kernel(
    const float* __restrict__ ac,
    const float* __restrict__ alpha,
    const float* __restrict__ Wkey_,
    const float* __restrict__ u,
    const float* __restrict__ bias,
    const float* __restrict__ q,
    const float* __restrict__ kws,
    const u16* __restrict__ XT,
    const u16* __restrict__ Wt,
    float* __restrict__ out)
{
    __shared__ u16  sP[MROWS * 256];   // 32 KB, chunk^=(m&15) swizzle
    __shared__ float sKU[4608];        // sK[256][16]+sU[256][2]; reused as sVals u16[16][520]
    __shared__ float sC[MROWS * 8];
    __shared__ float sRed[4 * MROWS];
    __shared__ float sInvS[MROWS];

    const int tid = threadIdx.x;
    const int bid = blockIdx.x;
    const int ch = bid & 31;
    const int f  = (bid >> 5) & 7;
    const int b  = bid >> 8;
    const int bf = b * NF + f;
    const int t0 = ch * TT;

    // ---- stage K (fp32) and U ----
    {
        const float4* k4 = (const float4*)(kws + ((size_t)bf << 12));
        float4* d4 = (float4*)sKU;
        #pragma unroll
        for (int i = 0; i < 4; ++i) d4[i * 256 + tid] = k4[i * 256 + tid];
        if (tid < 128) ((float4*)(sKU + 4096))[tid] = ((const float4*)(u + f * 512))[tid];
    }
    __syncthreads();
    // ---- per-row constants ----
    if (tid < MROWS) {
        int m = tid, h = m & 7, t = t0 + (m >> 3);
        float q0 = q[((size_t)(bf * NT + t) << 4) + h * 2];
        float q1 = q[((size_t)(bf * NT + t) << 4) + h * 2 + 1];
        float kt0 = sKU[t * 16 + h * 2], kt1 = sKU[t * 16 + h * 2 + 1];
        float al = alpha[f];
        float a0 = q0 - al;
        float a1 = q1 + 2.f * al * ac[f * 8 + h];
        float wk0 = Wkey_[f * 4], wk1 = Wkey_[f * 4 + 1];
        float wk2 = Wkey_[f * 4 + 2], wk3 = Wkey_[f * 4 + 3];
        float* cc = sC + m * 8;
        cc[0] = q0; cc[1] = q1; cc[2] = kt0; cc[3] = kt1;
        cc[4] = a0 * wk0 + a1 * wk2;   // c2
        cc[5] = a0 * wk1 + a1 * wk3;   // c1
    }
    __syncthreads();

    const int m  = tid & 63;
    const int lq = tid >> 6;
    const int t  = t0 + (m >> 3);
    const int h  = m & 7;
    float q0, q1, kt0, kt1, c2, c1;
    {
        const float* cc = sC + m * 8;
        q0 = cc[0]; q1 = cc[1]; kt0 = cc[2]; kt1 = cc[3]; c2 = cc[4]; c1 = cc[5];
    }
    const float* sKp = sKU;
    const float* sUp = sKU + 4096;

    // ---- pass A: max ----
    float mx = -1e30f;
    {
        float rel = (float)(lq * 64 - t);
        #pragma unroll 8
        for (int j = 0; j < 64; ++j) {
            int l = lq * 64 + j;
            float2 K = *(const float2*)(sKp + l * 16 + h * 2);
            float2 U = *(const float2*)(sUp + l * 2);
            float s = (c2 * rel + c1) * rel;
            s = fmaf(q0, K.x, s); s = fmaf(q1, K.y, s);
            s = fmaf(kt0, U.x, s); s = fmaf(kt1, U.y, s);
            mx = fmaxf(mx, s);
            rel += 1.f;
        }
    }
    sRed[lq * 64 + m] = mx;
    __syncthreads();
    const float M = fmaxf(fmaxf(sRed[m], sRed[64 + m]), fmaxf(sRed[128 + m], sRed[192 + m]));
    __syncthreads();

    // ---- pass B: exp, sum, write P (bf16, unnormalized) ----
    float sum = 0.f;
    {
        float rel = (float)(lq * 64 - t);
        unsigned pk[4]; float ep = 0.f;
        #pragma unroll 8
        for (int j = 0; j < 64; ++j) {
            int l = lq * 64 + j;
            float2 K = *(const float2*)(sKp + l * 16 + h * 2);
            float2 U = *(const float2*)(sUp + l * 2);
            float s = (c2 * rel + c1) * rel;
            s = fmaf(q0, K.x, s); s = fmaf(q1, K.y, s);
            s = fmaf(kt0, U.x, s); s = fmaf(kt1, U.y, s);
            float e = __expf(s - M);
            sum += e;
            if ((j & 1) == 0) ep = e;
            else pk[(j & 7) >> 1] = pk2(ep, e);
            if ((j & 7) == 7) {
                int chunk = l >> 3;
                int phys = chunk ^ (m & 15);
                *(u32x4*)&sP[m * 256 + phys * 8] = (u32x4){pk[0], pk[1], pk[2], pk[3]};
            }
            rel += 1.f;
        }
    }
    sRed[lq * 64 + m] = sum;
    __syncthreads();
    if (tid < MROWS)
        sInvS[tid] = 1.f / ((sRed[tid] + sRed[64 + tid]) + (sRed[128 + tid] + sRed[192 + tid]));
    __syncthreads();

    // ---- phase 3: vals = P @ X via MFMA (M=64, K=256, N=64) ----
    const int wv   = tid >> 6;
    const int lane = tid & 63;
    const int quad = lane >> 4;
    const int ln   = lane & 15;

    f32x4 acc0 = {0.f, 0.f, 0.f, 0.f}, acc1 = acc0, acc2 = acc0, acc3 = acc0;
    const u16* xb = XT + ((size_t)bf << 14);
    #pragma unroll
    for (int ks = 0; ks < 8; ++ks) {
        int chunk = ks * 4 + quad;
        int phys = chunk ^ ln;
        short8 a = *(const short8*)&sP[(wv * 16 + ln) * 256 + phys * 8];
        int l = ks * 32 + quad * 8;
        short8 b0 = *(const short8*)(xb + (0 * 16 + ln) * 256 + l);
        short8 b1 = *(const short8*)(xb + (1 * 16 + ln) * 256 + l);
        short8 b2 = *(const short8*)(xb + (2 * 16 + ln) * 256 + l);
        short8 b3 = *(const short8*)(xb + (3 * 16 + ln) * 256 + l);
        acc0 = __builtin_amdgcn_mfma_f32_16x16x32_bf16(a, b0, acc0, 0, 0, 0);
        acc1 = __builtin_amdgcn_mfma_f32_16x16x32_bf16(a, b1, acc1, 0, 0, 0);
        acc2 = __builtin_amdgcn_mfma_f32_16x16x32_bf16(a, b2, acc2, 0, 0, 0);
        acc3 = __builtin_amdgcn_mfma_f32_16x16x32_bf16(a, b3, acc3, 0, 0, 0);
    }

    u16* sVals = (u16*)sKU;   // [t][520]
    #pragma unroll
    for (int reg = 0; reg < 4; ++reg) {
        int mg = wv * 16 + quad * 4 + reg;
        float inv = sInvS[mg];
        int tl = mg >> 3, hh = mg & 7;
        u16* dst = sVals + tl * 520 + hh * 64 + ln;
        dst[0]  = f2bf(acc0[reg] * inv);
        dst[16] = f2bf(acc1[reg] * inv);
        dst[32] = f2bf(acc2[reg] * inv);
        dst[48] = f2bf(acc3[reg] * inv);
    }
    __syncthreads();

    // ---- phase 4: out = vals @ W via MFMA (M=8(pad16), K=512, N=64) ----
    f32x4 oacc = {0.f, 0.f, 0.f, 0.f};
    const u16* wb = Wt + ((size_t)(f * 64 + wv * 16 + ln) << 9);
    #pragma unroll
    for (int ks = 0; ks < 16; ++ks) {
        int k2 = ks * 32 + quad * 8;
        short8 a = *(const short8*)(sVals + ln * 520 + k2);
        short8 bw = *(const short8*)(wb + k2);
        oacc = __builtin_amdgcn_mfma_f32_16x16x32_bf16(a, bw, oacc, 0, 0, 0);
    }
    {
        int o = wv * 16 + ln;
        #pragma unroll
        for (int reg = 0; reg < 4; ++reg) {
            int tl = quad * 4 + reg;
            if (tl < TT) {
                int tg = t0 + tl;
                out[((size_t)(bf * NT + tg) << 6) + o] =
                    oacc[reg] + bias[((size_t)(f * NT + tg) << 6) + o];
            }
        }
    }
}

extern "C" void kernel_launch(void* const* d_in, const int* in_sizes, int n_in,
                              void* d_out, int out_size, void* d_ws, size_t ws_size,
                              hipStream_t stream) {
    const float* X     = (const float*)d_in[0];
    const float* ac    = (const float*)d_in[1];
    const float* alpha = (const float*)d_in[2];
    const float* Wq    = (const float*)d_in[3];
    const float* Wk    = (const float*)d_in[4];
    const float* Wkey_ = (const float*)d_in[5];
    const float* u     = (const float*)d_in[6];
    const float* W     = (const float*)d_in[7];
    const float* bb    = (const float*)d_in[8];
    float* out = (float*)d_out;

    float* qws = (float*)d_ws;                  // 131072 f
    float* kws = qws + 131072;                  // 131072 f
    u16* XT = (u16*)(kws + 131072);             // 524288 u16
    u16* Wt = XT + 524288;                      // 262144 u16

    hipLaunchKernelGGL(prep_kernel, dim3(2144), dim3(256), 0, stream,
                       X, Wq, Wk, W, qws, kws, XT, Wt);
    hipLaunchKernelGGL(attn_kernel, dim3(BS * NF * NCHUNK), dim3(256), 0, stream,
                       ac, alpha, Wkey_, u, bb, qws, kws, XT, Wt, out);
}

// Round 5
// 135.630 us; speedup vs baseline: 1.0155x; 1.0155x over previous
//
#include <hip/hip_runtime.h>
#include <hip/hip_bf16.h>

#define BS 4
#define NF 8
#define NT 256
#define DIN 64
#define NH 8
#define DOUT 64
#define TT 8          // t's per attn block
#define MROWS 64      // TT*NH score rows per block
#define NCHUNK 32     // NT/TT

typedef unsigned short u16;
typedef __attribute__((ext_vector_type(8))) short short8;
typedef __attribute__((ext_vector_type(4))) float f32x4;
typedef __attribute__((ext_vector_type(4))) unsigned int u32x4;

static __device__ __forceinline__ u16 f2bf(float x) {
    __hip_bfloat16 h = __float2bfloat16(x);
    u16 r; __builtin_memcpy(&r, &h, 2); return r;
}
static __device__ __forceinline__ unsigned pk2(float a, float b) {
    return (unsigned)f2bf(a) | ((unsigned)f2bf(b) << 16);
}

// ---------------------------------------------------------------------------
// prep: [0,1024) qk projection, wave-per-(which,f,t), no LDS, no barrier.
//       [1024,1056) X -> XT bf16 [bf][d][l] ; [1056,1120) W -> Wt bf16 [f][o][kk]
// qk wave: lane = (dg<<4)|(b<<2)|hq. Lane accumulates out[b, hq*4..+3] over
// d in [dg*16, dg*16+16): W float4 reads are 64B-contiguous per dg group
// (4x 64B segments/instr, each element fetched once; b-duplicates broadcast).
// 2-step shfl_xor(16,32) reduce over dg, float4 store by dg==0 lanes.
// ---------------------------------------------------------------------------
__global__ __launch_bounds__(256) void prep_kernel(
    const float* __restrict__ X,
    const float* __restrict__ Wq,
    const float* __restrict__ Wk,
    const float* __restrict__ W,
    float* __restrict__ q,
    float* __restrict__ k,
    u16* __restrict__ XT,
    u16* __restrict__ Wt)
{
    __shared__ float sT[64][65];
    const int tid = threadIdx.x;
    const int bid = blockIdx.x;

    if (bid < 1024) {
        const int gw = (bid << 2) + (tid >> 6);   // global wave
        const int which = gw >> 11;
        const int ft = gw & 2047;                 // f*NT + t
        const int f = ft >> 8, t = ft & 255;
        const int ln = tid & 63;
        const int dg = ln >> 4;
        const int b  = (ln >> 2) & 3;
        const int hq = ln & 3;

        const float* wmat = which ? Wk : Wq;
        const float* wp = wmat + ((size_t)ft << 10) + (dg << 8) + (hq << 2);
        const float* xp = X + (((size_t)((b * NF + f) * NT + t)) << 6) + (dg << 4);

        float4 acc = {0.f, 0.f, 0.f, 0.f};
        #pragma unroll
        for (int j = 0; j < 16; ++j) {
            float xv = xp[j];
            float4 w4 = *(const float4*)(wp + (j << 4));
            acc.x = fmaf(xv, w4.x, acc.x);
            acc.y = fmaf(xv, w4.y, acc.y);
            acc.z = fmaf(xv, w4.z, acc.z);
            acc.w = fmaf(xv, w4.w, acc.w);
        }
        #pragma unroll
        for (int off = 16; off <= 32; off <<= 1) {
            acc.x += __shfl_xor(acc.x, off);
            acc.y += __shfl_xor(acc.y, off);
            acc.z += __shfl_xor(acc.z, off);
            acc.w += __shfl_xor(acc.w, off);
        }
        if (dg == 0) {
            float* outp = which ? k : q;
            *(float4*)(outp + (((size_t)((b * NF + f) * NT + t)) << 4) + (hq << 2)) = acc;
        }
    } else if (bid < 1056) {
        const int bf = bid - 1024;
        for (int lc = 0; lc < 4; ++lc) {
            #pragma unroll
            for (int i = 0; i < 16; ++i) {
                int l = i * 4 + (tid >> 6), d = tid & 63;
                sT[l][d] = X[(((size_t)(bf * NT) + lc * 64 + l) << 6) + d];
            }
            __syncthreads();
            #pragma unroll
            for (int i = 0; i < 16; ++i) {
                int d = i * 4 + (tid >> 6), l = tid & 63;
                XT[(((size_t)(bf * 64) + d) << 8) + lc * 64 + l] = f2bf(sT[l][d]);
            }
            __syncthreads();
        }
    } else {
        const int idx = bid - 1056;
        const int f = idx >> 3, kc = idx & 7;
        #pragma unroll
        for (int i = 0; i < 16; ++i) {
            int kk = i * 4 + (tid >> 6), o = tid & 63;
            sT[kk][o] = W[(((size_t)(f * 512) + kc * 64 + kk) << 6) + o];
        }
        __syncthreads();
        #pragma unroll
        for (int i = 0; i < 16; ++i) {
            int o = i * 4 + (tid >> 6), kk = tid & 63;
            Wt[(((size_t)(f * 64) + o) << 9) + kc * 64 + kk] = f2bf(sT[kk][o]);
        }
    }
}

// ---------------------------------------------------------------------------
// attn: block = (b, f, 8-t chunk). 52.5 KB LDS -> 3 blocks/CU.
// Scores fp32 (2-pass softmax, 2 t-rows per thread per K/U read) ->
// P bf16 LDS (swizzled A-layout) -> pipelined MFMA P@X -> MFMA vals@W.
// ---------------------------------------------------------------------------
__global__ __launch_bounds__(256, 3) void attn_kernel(
    const float* __restrict__ ac,
    const float* __restrict__ alpha,
    const float* __restrict__ Wkey_,
    const float* __restrict__ u,
    const float* __restrict__ bias,
    const float* __restrict__ q,
    const float* __restrict__ kws,
    const u16* __restrict__ XT,
    const u16* __restrict__ Wt,
    float* __restrict__ out)
{
    __shared__ u16  sP[MROWS * 256];   // 32 KB, chunk^=(m&15) swizzle
    __shared__ float sKU[4608];        // K[l*16+h*2+e] + U@4096[l*2+e]; reused as sVals u16[16][520]
    __shared__ float sRed[8 * MROWS];  // 2 KB
    __shared__ float sM[MROWS];
    __shared__ float sInvS[MROWS];

    const int tid = threadIdx.x;
    const int bid = blockIdx.x;
    const int ch = bid & 31;
    const int f  = (bid >> 5) & 7;
    const int b  = bid >> 8;
    const int bf = b * NF + f;
    const int t0 = ch * TT;

    // ---- stage K (fp32) and U ----
    {
        const float4* k4 = (const float4*)(kws + ((size_t)bf << 12));
        float4* d4 = (float4*)sKU;
        #pragma unroll
        for (int i = 0; i < 4; ++i) d4[i * 256 + tid] = k4[i * 256 + tid];
        if (tid < 128) ((float4*)(sKU + 4096))[tid] = ((const float4*)(u + f * 512))[tid];
    }
    __syncthreads();

    const int h  = tid & 7;
    const int tp = (tid >> 3) & 3;
    const int le = tid >> 5;          // 0..7
    const int t_a = t0 + tp * 2, t_b = t_a + 1;
    const int m_a = tp * 16 + h, m_b = m_a + 8;
    const int lbase = le * 32;

    // ---- per-row constants (registers, 2 rows per thread) ----
    float q0a, q1a, kt0a, kt1a, c2a, c1a;
    float q0b, q1b, kt0b, kt1b, c2b, c1b;
    {
        float al = alpha[f];
        float acv = ac[f * 8 + h];
        float wk0 = Wkey_[f * 4],     wk1 = Wkey_[f * 4 + 1];
        float wk2 = Wkey_[f * 4 + 2], wk3 = Wkey_[f * 4 + 3];
        float2 qa = *(const float2*)(q + ((size_t)(bf * NT + t_a) << 4) + (h << 1));
        float2 qb = *(const float2*)(q + ((size_t)(bf * NT + t_b) << 4) + (h << 1));
        q0a = qa.x; q1a = qa.y; q0b = qb.x; q1b = qb.y;
        kt0a = sKU[t_a * 16 + h * 2]; kt1a = sKU[t_a * 16 + h * 2 + 1];
        kt0b = sKU[t_b * 16 + h * 2]; kt1b = sKU[t_b * 16 + h * 2 + 1];
        float a0 = q0a - al, a1 = q1a + 2.f * al * acv;
        c2a = a0 * wk0 + a1 * wk2; c1a = a0 * wk1 + a1 * wk3;
        a0 = q0b - al; a1 = q1b + 2.f * al * acv;
        c2b = a0 * wk0 + a1 * wk2; c1b = a0 * wk1 + a1 * wk3;
    }

    // ---- pass A: max over l (2 rows) ----
    float mxa = -1e30f, mxb = -1e30f;
    {
        float rela = (float)(lbase - t_a);
        #pragma unroll 8
        for (int j = 0; j < 32; ++j) {
            int l = lbase + j;
            float2 K = *(const float2*)(sKU + l * 16 + h * 2);
            float2 U = *(const float2*)(sKU + 4096 + l * 2);
            float relb = rela - 1.f;
            float sa = (c2a * rela + c1a) * rela;
            sa = fmaf(q0a, K.x, sa); sa = fmaf(q1a, K.y, sa);
            sa = fmaf(kt0a, U.x, sa); sa = fmaf(kt1a, U.y, sa);
            float sb = (c2b * relb + c1b) * relb;
            sb = fmaf(q0b, K.x, sb); sb = fmaf(q1b, K.y, sb);
            sb = fmaf(kt0b, U.x, sb); sb = fmaf(kt1b, U.y, sb);
            mxa = fmaxf(mxa, sa); mxb = fmaxf(mxb, sb);
            rela += 1.f;
        }
    }
    sRed[le * 64 + m_a] = mxa;
    sRed[le * 64 + m_b] = mxb;
    __syncthreads();
    if (tid < 64) {
        float mm = sRed[tid];
        #pragma unroll
        for (int i = 1; i < 8; ++i) mm = fmaxf(mm, sRed[i * 64 + tid]);
        sM[tid] = mm;
    }
    __syncthreads();

    // ---- pass B: exp, sums, P writes (bf16, unnormalized) ----
    {
        const float Ma = sM[m_a], Mb = sM[m_b];
        float suma = 0.f, sumb = 0.f;
        float rela = (float)(lbase - t_a);
        unsigned pka[4], pkb[4];
        float epa = 0.f, epb = 0.f;
        #pragma unroll 8
        for (int j = 0; j < 32; ++j) {
            int l = lbase + j;
            float2 K = *(const float2*)(sKU + l * 16 + h * 2);
            float2 U = *(const float2*)(sKU + 4096 + l * 2);
            float relb = rela - 1.f;
            float sa = (c2a * rela + c1a) * rela;
            sa = fmaf(q0a, K.x, sa); sa = fmaf(q1a, K.y, sa);
            sa = fmaf(kt0a, U.x, sa); sa = fmaf(kt1a, U.y, sa);
            float sb = (c2b * relb + c1b) * relb;
            sb = fmaf(q0b, K.x, sb); sb = fmaf(q1b, K.y, sb);
            sb = fmaf(kt0b, U.x, sb); sb = fmaf(kt1b, U.y, sb);
            float ea = __expf(sa - Ma), eb = __expf(sb - Mb);
            suma += ea; sumb += eb;
            if ((j & 1) == 0) { epa = ea; epb = eb; }
            else { pka[(j & 7) >> 1] = pk2(epa, ea); pkb[(j & 7) >> 1] = pk2(epb, eb); }
            if ((j & 7) == 7) {
                int chunk = l >> 3;
                int pa = chunk ^ (m_a & 15), pb = chunk ^ (m_b & 15);
                *(u32x4*)&sP[m_a * 256 + pa * 8] = (u32x4){pka[0], pka[1], pka[2], pka[3]};
                *(u32x4*)&sP[m_b * 256 + pb * 8] = (u32x4){pkb[0], pkb[1], pkb[2], pkb[3]};
            }
            rela += 1.f;
        }
        sRed[le * 64 + m_a] = suma;
        sRed[le * 64 + m_b] = sumb;
    }

    // ---- prefetch XT ks=0 b-frags (global, LDS-independent) across barriers
    const int wv   = tid >> 6;
    const int lane = tid & 63;
    const int quad = lane >> 4;
    const int ln   = lane & 15;
    const u16* xb = XT + ((size_t)bf << 14);
    short8 nb0, nb1, nb2, nb3;
    {
        int l = quad * 8;
        nb0 = *(const short8*)(xb + (0 * 16 + ln) * 256 + l);
        nb1 = *(const short8*)(xb + (1 * 16 + ln) * 256 + l);
        nb2 = *(const short8*)(xb + (2 * 16 + ln) * 256 + l);
        nb3 = *(const short8*)(xb + (3 * 16 + ln) * 256 + l);
    }
    __syncthreads();
    if (tid < 64) {
        float ss = sRed[tid];
        #pragma unroll
        for (int i = 1; i < 8; ++i) ss += sRed[i * 64 + tid];
        sInvS[tid] = 1.f / ss;
    }
    __syncthreads();

    // ---- phase 3: vals = P @ X via pipelined MFMA (M=64, K=256, N=64) ----
    f32x4 acc0 = {0.f, 0.f, 0.f, 0.f}, acc1 = acc0, acc2 = acc0, acc3 = acc0;
    #pragma unroll
    for (int ks = 0; ks < 8; ++ks) {
        short8 b0 = nb0, b1 = nb1, b2 = nb2, b3 = nb3;
        if (ks < 7) {
            int l = (ks + 1) * 32 + quad * 8;
            nb0 = *(const short8*)(xb + (0 * 16 + ln) * 256 + l);
            nb1 = *(const short8*)(xb + (1 * 16 + ln) * 256 + l);
            nb2 = *(const short8*)(xb + (2 * 16 + ln) * 256 + l);
            nb3 = *(const short8*)(xb + (3 * 16 + ln) * 256 + l);
        }
        int phys = (ks * 4 + quad) ^ ln;
        short8 a = *(const short8*)&sP[(wv * 16 + ln) * 256 + phys * 8];
        acc0 = __builtin_amdgcn_mfma_f32_16x16x32_bf16(a, b0, acc0, 0, 0, 0);
        acc1 = __builtin_amdgcn_mfma_f32_16x16x32_bf16(a, b1, acc1, 0, 0, 0);
        acc2 = __builtin_amdgcn_mfma_f32_16x16x32_bf16(a, b2, acc2, 0, 0, 0);
        acc3 = __builtin_amdgcn_mfma_f32_16x16x32_bf16(a, b3, acc3, 0, 0, 0);
    }

    u16* sVals = (u16*)sKU;   // [t][520], overlays K/U (dead after pass B)
    #pragma unroll
    for (int reg = 0; reg < 4; ++reg) {
        int mg = wv * 16 + quad * 4 + reg;
        float inv = sInvS[mg];
        int tl = mg >> 3, hh = mg & 7;
        u16* dst = sVals + tl * 520 + hh * 64 + ln;
        dst[0]  = f2bf(acc0[reg] * inv);
        dst[16] = f2bf(acc1[reg] * inv);
        dst[32] = f2bf(acc2[reg] * inv);
        dst[48] = f2bf(acc3[reg] * inv);
    }
    const u16* wb = Wt + ((size_t)(f * 64 + wv * 16 + ln) << 9);
    short8 nw = *(const short8*)(wb + quad * 8);   // prefetch ks=0 before barrier
    __syncthreads();

    // ---- phase 4: out = vals @ W via pipelined MFMA (M=8(pad16), K=512) ----
    f32x4 oacc = {0.f, 0.f, 0.f, 0.f};
    #pragma unroll
    for (int ks = 0; ks < 16; ++ks) {
        short8 bw = nw;
        if (ks < 15) nw = *(const short8*)(wb + (ks + 1) * 32 + quad * 8);
        short8 a = *(const short8*)(sVals + ln * 520 + ks * 32 + quad * 8);
        oacc = __builtin_amdgcn_mfma_f32_16x16x32_bf16(a, bw, oacc, 0, 0, 0);
    }
    {
        int o = wv * 16 + ln;
        #pragma unroll
        for (int reg = 0; reg < 4; ++reg) {
            int tl = quad * 4 + reg;
            if (tl < TT) {
                int tg = t0 + tl;
                out[((size_t)(bf * NT + tg) << 6) + o] =
                    oacc[reg] + bias[((size_t)(f * NT + tg) << 6) + o];
            }
        }
    }
}

extern "C" void kernel_launch(void* const* d_in, const int* in_sizes, int n_in,
                              void* d_out, int out_size, void* d_ws, size_t ws_size,
                              hipStream_t stream) {
    const float* X     = (const float*)d_in[0];
    const float* ac    = (const float*)d_in[1];
    const float* alpha = (const float*)d_in[2];
    const float* Wq    = (const float*)d_in[3];
    const float* Wk    = (const float*)d_in[4];
    const float* Wkey_ = (const float*)d_in[5];
    const float* u     = (const float*)d_in[6];
    const float* W     = (const float*)d_in[7];
    const float* bb    = (const float*)d_in[8];
    float* out = (float*)d_out;

    float* qws = (float*)d_ws;                  // 131072 f
    float* kws = qws + 131072;                  // 131072 f
    u16* XT = (u16*)(kws + 131072);             // 524288 u16
    u16* Wt = XT + 524288;                      // 262144 u16

    hipLaunchKernelGGL(prep_kernel, dim3(1120), dim3(256), 0, stream,
                       X, Wq, Wk, W, qws, kws, XT, Wt);
    hipLaunchKernelGGL(attn_kernel, dim3(BS * NF * NCHUNK), dim3(256), 0, stream,
                       ac, alpha, Wkey_, u, bb, qws, kws, XT, Wt, out);
}

// Round 6
// 119.009 us; speedup vs baseline: 1.1573x; 1.1397x over previous
//
#include <hip/hip_runtime.h>
#include <hip/hip_bf16.h>

#define BS 4
#define NF 8
#define NT 256
#define DIN 64
#define NH 8
#define DOUT 64
#define TT 4          // t's per attn block
#define MROWS 32      // TT*NH score rows per block
#define NCH 64        // NT/TT

typedef unsigned short u16;
typedef __attribute__((ext_vector_type(8))) short short8;
typedef __attribute__((ext_vector_type(4))) float f32x4;
typedef __attribute__((ext_vector_type(4))) unsigned int u32x4;

static __device__ __forceinline__ u16 f2bf(float x) {
    __hip_bfloat16 h = __float2bfloat16(x);
    u16 r; __builtin_memcpy(&r, &h, 2); return r;
}
static __device__ __forceinline__ unsigned pk2(float a, float b) {
    return (unsigned)f2bf(a) | ((unsigned)f2bf(b) << 16);
}

// ---------------------------------------------------------------------------
// prep: [0,1024) qk projection: wave = (which, f, t). W streamed as 4
//   lane-contiguous dwordx4 (every byte fetched once), X staged per-wave in
//   LDS (no barriers), butterfly shfl reduce over lane bits 2..5.
//   [1024,1056) X -> XT bf16 [bf][d][l] ; [1056,1120) W -> Wt bf16 [f][o][kk]
// ---------------------------------------------------------------------------
__global__ __launch_bounds__(256) void prep_kernel(
    const float* __restrict__ X,
    const float* __restrict__ Wq,
    const float* __restrict__ Wk,
    const float* __restrict__ W,
    float* __restrict__ q,
    float* __restrict__ k,
    u16* __restrict__ XT,
    u16* __restrict__ Wt)
{
    __shared__ float sT[64][65];
    __shared__ float sXq[4 * 256];
    const int tid = threadIdx.x;
    const int bid = blockIdx.x;

    if (bid < 1024) {
        const int wv = tid >> 6, L = tid & 63;
        const int gw = (bid << 2) + wv;      // 0..4095
        const int which = gw >> 11;
        const int ft = gw & 2047;            // f*NT + t
        const int f = ft >> 8, t = ft & 255;

        const float* wmat = which ? Wk : Wq;
        const float* wp = wmat + ((size_t)ft << 10);
        float4 w0 = *(const float4*)(wp + (L << 2));
        float4 w1 = *(const float4*)(wp + 256 + (L << 2));
        float4 w2 = *(const float4*)(wp + 512 + (L << 2));
        float4 w3 = *(const float4*)(wp + 768 + (L << 2));

        // stage X tile for this wave: lane L -> b = L>>4, d-quad = (L&15)*4
        float* sx = sXq + (wv << 8);
        {
            int xb = L >> 4, d4 = (L & 15) << 2;
            *(float4*)(sx + (xb << 6) + d4) =
                *(const float4*)(X + (((size_t)((xb * NF + f) * NT + t)) << 6) + d4);
        }
        // wave-synchronous LDS use: no barrier needed (same wave writes+reads)
        const int dr = L >> 2;               // d row within each 16-group
        float4 acc[4];
        #pragma unroll
        for (int bb = 0; bb < 4; ++bb) {
            float x0 = sx[(bb << 6) + dr];
            float x1 = sx[(bb << 6) + 16 + dr];
            float x2 = sx[(bb << 6) + 32 + dr];
            float x3 = sx[(bb << 6) + 48 + dr];
            float4 a;
            a.x = fmaf(x0, w0.x, fmaf(x1, w1.x, fmaf(x2, w2.x, x3 * w3.x)));
            a.y = fmaf(x0, w0.y, fmaf(x1, w1.y, fmaf(x2, w2.y, x3 * w3.y)));
            a.z = fmaf(x0, w0.z, fmaf(x1, w1.z, fmaf(x2, w2.z, x3 * w3.z)));
            a.w = fmaf(x0, w0.w, fmaf(x1, w1.w, fmaf(x2, w2.w, x3 * w3.w)));
            acc[bb] = a;
        }
        #pragma unroll
        for (int off = 4; off <= 32; off <<= 1) {
            #pragma unroll
            for (int bb = 0; bb < 4; ++bb) {
                acc[bb].x += __shfl_xor(acc[bb].x, off);
                acc[bb].y += __shfl_xor(acc[bb].y, off);
                acc[bb].z += __shfl_xor(acc[bb].z, off);
                acc[bb].w += __shfl_xor(acc[bb].w, off);
            }
        }
        if (L < 4) {
            float* outp = which ? k : q;
            #pragma unroll
            for (int bb = 0; bb < 4; ++bb)
                *(float4*)(outp + (((size_t)((bb * NF + f) * NT + t)) << 4) + (L << 2)) = acc[bb];
        }
    } else if (bid < 1056) {
        const int bf = bid - 1024;
        for (int lc = 0; lc < 4; ++lc) {
            #pragma unroll
            for (int i = 0; i < 16; ++i) {
                int l = i * 4 + (tid >> 6), d = tid & 63;
                sT[l][d] = X[(((size_t)(bf * NT) + lc * 64 + l) << 6) + d];
            }
            __syncthreads();
            #pragma unroll
            for (int i = 0; i < 16; ++i) {
                int d = i * 4 + (tid >> 6), l = tid & 63;
                XT[(((size_t)(bf * 64) + d) << 8) + lc * 64 + l] = f2bf(sT[l][d]);
            }
            __syncthreads();
        }
    } else {
        const int idx = bid - 1056;
        const int f = idx >> 3, kc = idx & 7;
        #pragma unroll
        for (int i = 0; i < 16; ++i) {
            int kk = i * 4 + (tid >> 6), o = tid & 63;
            sT[kk][o] = W[(((size_t)(f * 512) + kc * 64 + kk) << 6) + o];
        }
        __syncthreads();
        #pragma unroll
        for (int i = 0; i < 16; ++i) {
            int o = i * 4 + (tid >> 6), kk = tid & 63;
            Wt[(((size_t)(f * 64) + o) << 9) + kc * 64 + kk] = f2bf(sT[kk][o]);
        }
    }
}

// ---------------------------------------------------------------------------
// attn: block = (b, f, 4-t chunk). 36.3 KB LDS -> 4 blocks/CU, grid 2048.
// Scores fp32 once (stashed in regs) -> max reduce -> exp-only pass ->
// P bf16 LDS (swizzled) -> MFMA P@X -> MFMA vals@W -> out.
// ---------------------------------------------------------------------------
__global__ __launch_bounds__(256, 4) void attn_kernel(
    const float* __restrict__ ac,
    const float* __restrict__ alpha,
    const float* __restrict__ Wkey_,
    const float* __restrict__ u,
    const float* __restrict__ bias,
    const float* __restrict__ q,
    const float* __restrict__ kws,
    const u16* __restrict__ XT,
    const u16* __restrict__ Wt,
    float* __restrict__ out)
{
    __shared__ u16  sP[MROWS * 256];   // 16 KB, chunk^(m&15) swizzle
    __shared__ float sKU[4608];        // K[l*16+h*2+e] + U@4096[l*2+e]; overlay sVals u16[16][520]
    __shared__ float sRed[MROWS * 16]; // 2 KB, [m][lg]
    __shared__ float sM[MROWS];
    __shared__ float sInvS[MROWS];

    const int tid = threadIdx.x;
    const int bid = blockIdx.x;
    const int ch = bid & 63;
    const int f  = (bid >> 6) & 7;
    const int b  = bid >> 9;
    const int bf = b * NF + f;
    const int t0 = ch * TT;

    // ---- stage K (fp32) and U ----
    {
        const float4* k4 = (const float4*)(kws + ((size_t)bf << 12));
        float4* d4 = (float4*)sKU;
        #pragma unroll
        for (int i = 0; i < 4; ++i) d4[i * 256 + tid] = k4[i * 256 + tid];
        if (tid < 128) ((float4*)(sKU + 4096))[tid] = ((const float4*)(u + f * 512))[tid];
    }
    __syncthreads();

    const int h  = tid & 7;
    const int tp = (tid >> 3) & 1;
    const int lg = tid >> 4;          // 0..15
    const int t_a = t0 + tp * 2, t_b = t_a + 1;
    const int m_a = tp * 16 + h, m_b = m_a + 8;   // m_a&15 = h, m_b&15 = h+8
    const int lbase = lg * 16;

    // ---- per-row constants (registers, 2 rows per thread) ----
    float q0a, q1a, kt0a, kt1a, c2a, c1a;
    float q0b, q1b, kt0b, kt1b, c2b, c1b;
    {
        float al = alpha[f];
        float acv = ac[f * 8 + h];
        float wk0 = Wkey_[f * 4],     wk1 = Wkey_[f * 4 + 1];
        float wk2 = Wkey_[f * 4 + 2], wk3 = Wkey_[f * 4 + 3];
        float2 qa = *(const float2*)(q + ((size_t)(bf * NT + t_a) << 4) + (h << 1));
        float2 qb = *(const float2*)(q + ((size_t)(bf * NT + t_b) << 4) + (h << 1));
        q0a = qa.x; q1a = qa.y; q0b = qb.x; q1b = qb.y;
        kt0a = sKU[t_a * 16 + h * 2]; kt1a = sKU[t_a * 16 + h * 2 + 1];
        kt0b = sKU[t_b * 16 + h * 2]; kt1b = sKU[t_b * 16 + h * 2 + 1];
        float a0 = q0a - al, a1 = q1a + 2.f * al * acv;
        c2a = a0 * wk0 + a1 * wk2; c1a = a0 * wk1 + a1 * wk3;
        a0 = q0b - al; a1 = q1b + 2.f * al * acv;
        c2b = a0 * wk0 + a1 * wk2; c1b = a0 * wk1 + a1 * wk3;
    }

    // ---- pass A: scores into registers + running max ----
    float sA[16], sB[16];
    float mxa = -1e30f, mxb = -1e30f;
    {
        float rela = (float)(lbase - t_a);
        #pragma unroll
        for (int j = 0; j < 16; ++j) {
            int l = lbase + j;
            float2 K = *(const float2*)(sKU + l * 16 + h * 2);
            float2 U = *(const float2*)(sKU + 4096 + l * 2);
            float relb = rela - 1.f;
            float sa = (c2a * rela + c1a) * rela;
            sa = fmaf(q0a, K.x, sa); sa = fmaf(q1a, K.y, sa);
            sa = fmaf(kt0a, U.x, sa); sa = fmaf(kt1a, U.y, sa);
            float sb = (c2b * relb + c1b) * relb;
            sb = fmaf(q0b, K.x, sb); sb = fmaf(q1b, K.y, sb);
            sb = fmaf(kt0b, U.x, sb); sb = fmaf(kt1b, U.y, sb);
            sA[j] = sa; sB[j] = sb;
            mxa = fmaxf(mxa, sa); mxb = fmaxf(mxb, sb);
            rela += 1.f;
        }
    }
    sRed[m_a * 16 + lg] = mxa;
    sRed[m_b * 16 + lg] = mxb;
    __syncthreads();
    if (tid < MROWS) {
        const float4* r4 = (const float4*)(sRed + tid * 16);
        float4 r0 = r4[0], r1 = r4[1], r2 = r4[2], r3 = r4[3];
        float mm = fmaxf(fmaxf(fmaxf(r0.x, r0.y), fmaxf(r0.z, r0.w)),
                         fmaxf(fmaxf(r1.x, r1.y), fmaxf(r1.z, r1.w)));
        mm = fmaxf(mm, fmaxf(fmaxf(fmaxf(r2.x, r2.y), fmaxf(r2.z, r2.w)),
                             fmaxf(fmaxf(r3.x, r3.y), fmaxf(r3.z, r3.w))));
        sM[tid] = mm;
    }
    __syncthreads();

    // ---- pass B: exp from regs, sums, P writes (bf16, unnormalized) ----
    {
        const float Ma = sM[m_a], Mb = sM[m_b];
        float suma = 0.f, sumb = 0.f;
        unsigned pka[4], pkb[4];
        float epa = 0.f, epb = 0.f;
        #pragma unroll
        for (int j = 0; j < 16; ++j) {
            float ea = __expf(sA[j] - Ma), eb = __expf(sB[j] - Mb);
            suma += ea; sumb += eb;
            if ((j & 1) == 0) { epa = ea; epb = eb; }
            else { pka[(j & 7) >> 1] = pk2(epa, ea); pkb[(j & 7) >> 1] = pk2(epb, eb); }
            if ((j & 7) == 7) {
                int chunk = lg * 2 + (j >> 3);
                int pa = chunk ^ h;
                int pb = chunk ^ (h + 8);
                *(u32x4*)&sP[m_a * 256 + pa * 8] = (u32x4){pka[0], pka[1], pka[2], pka[3]};
                *(u32x4*)&sP[m_b * 256 + pb * 8] = (u32x4){pkb[0], pkb[1], pkb[2], pkb[3]};
            }
        }
        sRed[m_a * 16 + lg] = suma;
        sRed[m_b * 16 + lg] = sumb;
    }

    // ---- prefetch XT ks=0 b-frags across the reduction barrier ----
    const int wv   = tid >> 6;
    const int lane = tid & 63;
    const int quad = lane >> 4;
    const int ln   = lane & 15;
    const int mh   = wv & 1;          // m-half for phase 3
    const int nh   = wv >> 1;         // n-half for phase 3
    const u16* xb = XT + ((size_t)bf << 14);
    short8 nb0, nb1;
    {
        int l2 = quad * 8;
        nb0 = *(const short8*)(xb + (nh * 32 + ln) * 256 + l2);
        nb1 = *(const short8*)(xb + (nh * 32 + 16 + ln) * 256 + l2);
    }
    __syncthreads();
    if (tid < MROWS) {
        const float4* r4 = (const float4*)(sRed + tid * 16);
        float4 r0 = r4[0], r1 = r4[1], r2 = r4[2], r3 = r4[3];
        float ss = ((r0.x + r0.y) + (r0.z + r0.w)) + ((r1.x + r1.y) + (r1.z + r1.w))
                 + ((r2.x + r2.y) + (r2.z + r2.w)) + ((r3.x + r3.y) + (r3.z + r3.w));
        sInvS[tid] = 1.f / ss;
    }
    __syncthreads();

    // ---- phase 3: vals = P @ X via pipelined MFMA (M=32, K=256, N=64) ----
    f32x4 acc0 = {0.f, 0.f, 0.f, 0.f}, acc1 = acc0;
    #pragma unroll
    for (int ks = 0; ks < 8; ++ks) {
        short8 b0 = nb0, b1 = nb1;
        if (ks < 7) {
            int l2 = (ks + 1) * 32 + quad * 8;
            nb0 = *(const short8*)(xb + (nh * 32 + ln) * 256 + l2);
            nb1 = *(const short8*)(xb + (nh * 32 + 16 + ln) * 256 + l2);
        }
        int phys = (ks * 4 + quad) ^ ln;
        short8 a = *(const short8*)&sP[(mh * 16 + ln) * 256 + phys * 8];
        acc0 = __builtin_amdgcn_mfma_f32_16x16x32_bf16(a, b0, acc0, 0, 0, 0);
        acc1 = __builtin_amdgcn_mfma_f32_16x16x32_bf16(a, b1, acc1, 0, 0, 0);
    }

    u16* sVals = (u16*)sKU;   // [t][520], overlays K/U (dead after pass A consts)
    #pragma unroll
    for (int reg = 0; reg < 4; ++reg) {
        int mg = mh * 16 + quad * 4 + reg;
        float inv = sInvS[mg];
        int tl = mg >> 3, hh = mg & 7;
        u16* dst = sVals + tl * 520 + hh * 64 + nh * 32 + ln;
        dst[0]  = f2bf(acc0[reg] * inv);
        dst[16] = f2bf(acc1[reg] * inv);
    }
    const u16* wb = Wt + ((size_t)(f * 64 + wv * 16 + ln) << 9);
    short8 nw = *(const short8*)(wb + quad * 8);   // prefetch ks=0 before barrier
    __syncthreads();

    // ---- phase 4: out = vals @ W via pipelined MFMA (M=4(pad16), K=512) ----
    f32x4 oacc = {0.f, 0.f, 0.f, 0.f};
    #pragma unroll
    for (int ks = 0; ks < 16; ++ks) {
        short8 bw = nw;
        if (ks < 15) nw = *(const short8*)(wb + (ks + 1) * 32 + quad * 8);
        short8 a = *(const short8*)(sVals + ln * 520 + ks * 32 + quad * 8);
        oacc = __builtin_amdgcn_mfma_f32_16x16x32_bf16(a, bw, oacc, 0, 0, 0);
    }
    {
        int o = wv * 16 + ln;
        #pragma unroll
        for (int reg = 0; reg < 4; ++reg) {
            int tl = quad * 4 + reg;
            if (tl < TT) {
                int tg = t0 + tl;
                out[((size_t)(bf * NT + tg) << 6) + o] =
                    oacc[reg] + bias[((size_t)(f * NT + tg) << 6) + o];
            }
        }
    }
}

extern "C" void kernel_launch(void* const* d_in, const int* in_sizes, int n_in,
                              void* d_out, int out_size, void* d_ws, size_t ws_size,
                              hipStream_t stream) {
    const float* X     = (const float*)d_in[0];
    const float* ac    = (const float*)d_in[1];
    const float* alpha = (const float*)d_in[2];
    const float* Wq    = (const float*)d_in[3];
    const float* Wk    = (const float*)d_in[4];
    const float* Wkey_ = (const float*)d_in[5];
    const float* u     = (const float*)d_in[6];
    const float* W     = (const float*)d_in[7];
    const float* bb    = (const float*)d_in[8];
    float* out = (float*)d_out;

    float* qws = (float*)d_ws;                  // 131072 f
    float* kws = qws + 131072;                  // 131072 f
    u16* XT = (u16*)(kws + 131072);             // 524288 u16
    u16* Wt = XT + 524288;                      // 262144 u16

    hipLaunchKernelGGL(prep_kernel, dim3(1120), dim3(256), 0, stream,
                       X, Wq, Wk, W, qws, kws, XT, Wt);
    hipLaunchKernelGGL(attn_kernel, dim3(BS * NF * NCH), dim3(256), 0, stream,
                       ac, alpha, Wkey_, u, bb, qws, kws, XT, Wt, out);
}

// Round 7
// 118.393 us; speedup vs baseline: 1.1633x; 1.0052x over previous
//
#include <hip/hip_runtime.h>
#include <hip/hip_bf16.h>

#define BS 4
#define NF 8
#define NT 256
#define DIN 64
#define NH 8
#define DOUT 64
#define TT 4          // t's per attn block
#define MROWS 32      // TT*NH score rows per block
#define NCH 64        // NT/TT

typedef unsigned short u16;
typedef __attribute__((ext_vector_type(8))) short short8;
typedef __attribute__((ext_vector_type(4))) float f32x4;
typedef __attribute__((ext_vector_type(4))) unsigned int u32x4;

static __device__ __forceinline__ u16 f2bf(float x) {
    __hip_bfloat16 h = __float2bfloat16(x);
    u16 r; __builtin_memcpy(&r, &h, 2); return r;
}
static __device__ __forceinline__ unsigned pk2(float a, float b) {
    return (unsigned)f2bf(a) | ((unsigned)f2bf(b) << 16);
}

// ---------------------------------------------------------------------------
// prep: [0,2048) qk projection, block per (f,t): Wq/Wk staged TRANSPOSED
//   ([which][he][d], stride 68) so compute reads are ds_read_b128; thread =
//   (which,b,he,half-d), serial 32-FMA dot, one shfl_xor(1) combine.
//   [2048,2176) X -> XT bf16 [bf][d][l] (128 blocks, one 64x64 tile each)
//   [2176,2240) W -> Wt bf16 [f][o][kk]
// ---------------------------------------------------------------------------
__global__ __launch_bounds__(256) void prep_kernel(
    const float* __restrict__ X,
    const float* __restrict__ Wq,
    const float* __restrict__ Wk,
    const float* __restrict__ W,
    float* __restrict__ q,
    float* __restrict__ k,
    u16* __restrict__ XT,
    u16* __restrict__ Wt)
{
    __shared__ float sm[4160];          // union: qk {sWt[2176], sX[256]} | sT[64][65]
    const int tid = threadIdx.x;
    const int bid = blockIdx.x;

    if (bid < 2048) {
        const int ft = bid;             // f*NT + t
        const int f = ft >> 8, t = ft & 255;
        float* sWt = sm;                // [which*1088 + he*68 + d]
        float* sX  = sm + 2176;         // [b*64 + d]

        // ---- stage W transposed: thread holds flat elems tid*4..+3 of each
        float4 a4 = ((const float4*)(Wq + ((size_t)ft << 10)))[tid];
        float4 b4 = ((const float4*)(Wk + ((size_t)ft << 10)))[tid];
        {
            int d = tid >> 2, he = (tid & 3) << 2;
            sWt[(he + 0) * 68 + d] = a4.x;
            sWt[(he + 1) * 68 + d] = a4.y;
            sWt[(he + 2) * 68 + d] = a4.z;
            sWt[(he + 3) * 68 + d] = a4.w;
            sWt[1088 + (he + 0) * 68 + d] = b4.x;
            sWt[1088 + (he + 1) * 68 + d] = b4.y;
            sWt[1088 + (he + 2) * 68 + d] = b4.z;
            sWt[1088 + (he + 3) * 68 + d] = b4.w;
            int xb = tid >> 6, xd = tid & 63;
            sX[tid] = X[(((size_t)((xb * NF + f) * NT + t)) << 6) + xd];
        }
        __syncthreads();

        // ---- compute: 2 threads per output (d halves), b128 LDS reads ----
        const int half  = tid & 1;
        const int he    = (tid >> 1) & 15;
        const int b     = (tid >> 5) & 3;
        const int which = tid >> 7;
        const float* wp = sWt + which * 1088 + he * 68 + (half << 5);
        const float* xp = sX + (b << 6) + (half << 5);
        float acc = 0.f;
        #pragma unroll
        for (int j = 0; j < 8; ++j) {
            float4 w = *(const float4*)(wp + (j << 2));
            float4 x = *(const float4*)(xp + (j << 2));
            acc = fmaf(w.x, x.x, acc);
            acc = fmaf(w.y, x.y, acc);
            acc = fmaf(w.z, x.z, acc);
            acc = fmaf(w.w, x.w, acc);
        }
        acc += __shfl_xor(acc, 1);
        if (half == 0) {
            float* outp = which ? k : q;
            outp[(((size_t)((b * NF + f) * NT + t)) << 4) + he] = acc;
        }
    } else if (bid < 2176) {
        const int idx = bid - 2048;     // (bf, lc)
        const int bf = idx >> 2, lc = idx & 3;
        float (*sT)[65] = (float(*)[65])sm;
        #pragma unroll
        for (int i = 0; i < 16; ++i) {
            int l = i * 4 + (tid >> 6), d = tid & 63;
            sT[l][d] = X[(((size_t)(bf * NT) + lc * 64 + l) << 6) + d];
        }
        __syncthreads();
        #pragma unroll
        for (int i = 0; i < 16; ++i) {
            int d = i * 4 + (tid >> 6), l = tid & 63;
            XT[(((size_t)(bf * 64) + d) << 8) + lc * 64 + l] = f2bf(sT[l][d]);
        }
    } else {
        const int idx = bid - 2176;
        const int f = idx >> 3, kc = idx & 7;
        float (*sT)[65] = (float(*)[65])sm;
        #pragma unroll
        for (int i = 0; i < 16; ++i) {
            int kk = i * 4 + (tid >> 6), o = tid & 63;
            sT[kk][o] = W[(((size_t)(f * 512) + kc * 64 + kk) << 6) + o];
        }
        __syncthreads();
        #pragma unroll
        for (int i = 0; i < 16; ++i) {
            int o = i * 4 + (tid >> 6), kk = tid & 63;
            Wt[(((size_t)(f * 64) + o) << 9) + kc * 64 + kk] = f2bf(sT[kk][o]);
        }
    }
}

// ---------------------------------------------------------------------------
// attn: block = (b, f, 4-t chunk). 36.3 KB LDS -> 4 blocks/CU, grid 2048.
// Scores fp32 once (stashed in regs) -> max reduce -> exp-only pass ->
// P bf16 LDS (swizzled) -> MFMA P@X -> MFMA vals@W -> out.
// (UNCHANGED from round 6 for clean attribution.)
// ---------------------------------------------------------------------------
__global__ __launch_bounds__(256, 4) void attn_kernel(
    const float* __restrict__ ac,
    const float* __restrict__ alpha,
    const float* __restrict__ Wkey_,
    const float* __restrict__ u,
    const float* __restrict__ bias,
    const float* __restrict__ q,
    const float* __restrict__ kws,
    const u16* __restrict__ XT,
    const u16* __restrict__ Wt,
    float* __restrict__ out)
{
    __shared__ u16  sP[MROWS * 256];   // 16 KB, chunk^(m&15) swizzle
    __shared__ float sKU[4608];        // K[l*16+h*2+e] + U@4096[l*2+e]; overlay sVals u16[16][520]
    __shared__ float sRed[MROWS * 16]; // 2 KB, [m][lg]
    __shared__ float sM[MROWS];
    __shared__ float sInvS[MROWS];

    const int tid = threadIdx.x;
    const int bid = blockIdx.x;
    const int ch = bid & 63;
    const int f  = (bid >> 6) & 7;
    const int b  = bid >> 9;
    const int bf = b * NF + f;
    const int t0 = ch * TT;

    // ---- stage K (fp32) and U ----
    {
        const float4* k4 = (const float4*)(kws + ((size_t)bf << 12));
        float4* d4 = (float4*)sKU;
        #pragma unroll
        for (int i = 0; i < 4; ++i) d4[i * 256 + tid] = k4[i * 256 + tid];
        if (tid < 128) ((float4*)(sKU + 4096))[tid] = ((const float4*)(u + f * 512))[tid];
    }
    __syncthreads();

    const int h  = tid & 7;
    const int tp = (tid >> 3) & 1;
    const int lg = tid >> 4;          // 0..15
    const int t_a = t0 + tp * 2, t_b = t_a + 1;
    const int m_a = tp * 16 + h, m_b = m_a + 8;   // m_a&15 = h, m_b&15 = h+8
    const int lbase = lg * 16;

    // ---- per-row constants (registers, 2 rows per thread) ----
    float q0a, q1a, kt0a, kt1a, c2a, c1a;
    float q0b, q1b, kt0b, kt1b, c2b, c1b;
    {
        float al = alpha[f];
        float acv = ac[f * 8 + h];
        float wk0 = Wkey_[f * 4],     wk1 = Wkey_[f * 4 + 1];
        float wk2 = Wkey_[f * 4 + 2], wk3 = Wkey_[f * 4 + 3];
        float2 qa = *(const float2*)(q + ((size_t)(bf * NT + t_a) << 4) + (h << 1));
        float2 qb = *(const float2*)(q + ((size_t)(bf * NT + t_b) << 4) + (h << 1));
        q0a = qa.x; q1a = qa.y; q0b = qb.x; q1b = qb.y;
        kt0a = sKU[t_a * 16 + h * 2]; kt1a = sKU[t_a * 16 + h * 2 + 1];
        kt0b = sKU[t_b * 16 + h * 2]; kt1b = sKU[t_b * 16 + h * 2 + 1];
        float a0 = q0a - al, a1 = q1a + 2.f * al * acv;
        c2a = a0 * wk0 + a1 * wk2; c1a = a0 * wk1 + a1 * wk3;
        a0 = q0b - al; a1 = q1b + 2.f * al * acv;
        c2b = a0 * wk0 + a1 * wk2; c1b = a0 * wk1 + a1 * wk3;
    }

    // ---- pass A: scores into registers + running max ----
    float sA[16], sB[16];
    float mxa = -1e30f, mxb = -1e30f;
    {
        float rela = (float)(lbase - t_a);
        #pragma unroll
        for (int j = 0; j < 16; ++j) {
            int l = lbase + j;
            float2 K = *(const float2*)(sKU + l * 16 + h * 2);
            float2 U = *(const float2*)(sKU + 4096 + l * 2);
            float relb = rela - 1.f;
            float sa = (c2a * rela + c1a) * rela;
            sa = fmaf(q0a, K.x, sa); sa = fmaf(q1a, K.y, sa);
            sa = fmaf(kt0a, U.x, sa); sa = fmaf(kt1a, U.y, sa);
            float sb = (c2b * relb + c1b) * relb;
            sb = fmaf(q0b, K.x, sb); sb = fmaf(q1b, K.y, sb);
            sb = fmaf(kt0b, U.x, sb); sb = fmaf(kt1b, U.y, sb);
            sA[j] = sa; sB[j] = sb;
            mxa = fmaxf(mxa, sa); mxb = fmaxf(mxb, sb);
            rela += 1.f;
        }
    }
    sRed[m_a * 16 + lg] = mxa;
    sRed[m_b * 16 + lg] = mxb;
    __syncthreads();
    if (tid < MROWS) {
        const float4* r4 = (const float4*)(sRed + tid * 16);
        float4 r0 = r4[0], r1 = r4[1], r2 = r4[2], r3 = r4[3];
        float mm = fmaxf(fmaxf(fmaxf(r0.x, r0.y), fmaxf(r0.z, r0.w)),
                         fmaxf(fmaxf(r1.x, r1.y), fmaxf(r1.z, r1.w)));
        mm = fmaxf(mm, fmaxf(fmaxf(fmaxf(r2.x, r2.y), fmaxf(r2.z, r2.w)),
                             fmaxf(fmaxf(r3.x, r3.y), fmaxf(r3.z, r3.w))));
        sM[tid] = mm;
    }
    __syncthreads();

    // ---- pass B: exp from regs, sums, P writes (bf16, unnormalized) ----
    {
        const float Ma = sM[m_a], Mb = sM[m_b];
        float suma = 0.f, sumb = 0.f;
        unsigned pka[4], pkb[4];
        float epa = 0.f, epb = 0.f;
        #pragma unroll
        for (int j = 0; j < 16; ++j) {
            float ea = __expf(sA[j] - Ma), eb = __expf(sB[j] - Mb);
            suma += ea; sumb += eb;
            if ((j & 1) == 0) { epa = ea; epb = eb; }
            else { pka[(j & 7) >> 1] = pk2(epa, ea); pkb[(j & 7) >> 1] = pk2(epb, eb); }
            if ((j & 7) == 7) {
                int chunk = lg * 2 + (j >> 3);
                int pa = chunk ^ h;
                int pb = chunk ^ (h + 8);
                *(u32x4*)&sP[m_a * 256 + pa * 8] = (u32x4){pka[0], pka[1], pka[2], pka[3]};
                *(u32x4*)&sP[m_b * 256 + pb * 8] = (u32x4){pkb[0], pkb[1], pkb[2], pkb[3]};
            }
        }
        sRed[m_a * 16 + lg] = suma;
        sRed[m_b * 16 + lg] = sumb;
    }

    // ---- prefetch XT ks=0 b-frags across the reduction barrier ----
    const int wv   = tid >> 6;
    const int lane = tid & 63;
    const int quad = lane >> 4;
    const int ln   = lane & 15;
    const int mh   = wv & 1;          // m-half for phase 3
    const int nh   = wv >> 1;         // n-half for phase 3
    const u16* xb = XT + ((size_t)bf << 14);
    short8 nb0, nb1;
    {
        int l2 = quad * 8;
        nb0 = *(const short8*)(xb + (nh * 32 + ln) * 256 + l2);
        nb1 = *(const short8*)(xb + (nh * 32 + 16 + ln) * 256 + l2);
    }
    __syncthreads();
    if (tid < MROWS) {
        const float4* r4 = (const float4*)(sRed + tid * 16);
        float4 r0 = r4[0], r1 = r4[1], r2 = r4[2], r3 = r4[3];
        float ss = ((r0.x + r0.y) + (r0.z + r0.w)) + ((r1.x + r1.y) + (r1.z + r1.w))
                 + ((r2.x + r2.y) + (r2.z + r2.w)) + ((r3.x + r3.y) + (r3.z + r3.w));
        sInvS[tid] = 1.f / ss;
    }
    __syncthreads();

    // ---- phase 3: vals = P @ X via pipelined MFMA (M=32, K=256, N=64) ----
    f32x4 acc0 = {0.f, 0.f, 0.f, 0.f}, acc1 = acc0;
    #pragma unroll
    for (int ks = 0; ks < 8; ++ks) {
        short8 b0 = nb0, b1 = nb1;
        if (ks < 7) {
            int l2 = (ks + 1) * 32 + quad * 8;
            nb0 = *(const short8*)(xb + (nh * 32 + ln) * 256 + l2);
            nb1 = *(const short8*)(xb + (nh * 32 + 16 + ln) * 256 + l2);
        }
        int phys = (ks * 4 + quad) ^ ln;
        short8 a = *(const short8*)&sP[(mh * 16 + ln) * 256 + phys * 8];
        acc0 = __builtin_amdgcn_mfma_f32_16x16x32_bf16(a, b0, acc0, 0, 0, 0);
        acc1 = __builtin_amdgcn_mfma_f32_16x16x32_bf16(a, b1, acc1, 0, 0, 0);
    }

    u16* sVals = (u16*)sKU;   // [t][520], overlays K/U (dead after pass A consts)
    #pragma unroll
    for (int reg = 0; reg < 4; ++reg) {
        int mg = mh * 16 + quad * 4 + reg;
        float inv = sInvS[mg];
        int tl = mg >> 3, hh = mg & 7;
        u16* dst = sVals + tl * 520 + hh * 64 + nh * 32 + ln;
        dst[0]  = f2bf(acc0[reg] * inv);
        dst[16] = f2bf(acc1[reg] * inv);
    }
    const u16* wb = Wt + ((size_t)(f * 64 + wv * 16 + ln) << 9);
    short8 nw = *(const short8*)(wb + quad * 8);   // prefetch ks=0 before barrier
    __syncthreads();

    // ---- phase 4: out = vals @ W via pipelined MFMA (M=4(pad16), K=512) ----
    f32x4 oacc = {0.f, 0.f, 0.f, 0.f};
    #pragma unroll
    for (int ks = 0; ks < 16; ++ks) {
        short8 bw = nw;
        if (ks < 15) nw = *(const short8*)(wb + (ks + 1) * 32 + quad * 8);
        short8 a = *(const short8*)(sVals + ln * 520 + ks * 32 + quad * 8);
        oacc = __builtin_amdgcn_mfma_f32_16x16x32_bf16(a, bw, oacc, 0, 0, 0);
    }
    {
        int o = wv * 16 + ln;
        #pragma unroll
        for (int reg = 0; reg < 4; ++reg) {
            int tl = quad * 4 + reg;
            if (tl < TT) {
                int tg = t0 + tl;
                out[((size_t)(bf * NT + tg) << 6) + o] =
                    oacc[reg] + bias[((size_t)(f * NT + tg) << 6) + o];
            }
        }
    }
}

extern "C" void kernel_launch(void* const* d_in, const int* in_sizes, int n_in,
                              void* d_out, int out_size, void* d_ws, size_t ws_size,
                              hipStream_t stream) {
    const float* X     = (const float*)d_in[0];
    const float* ac    = (const float*)d_in[1];
    const float* alpha = (const float*)d_in[2];
    const float* Wq    = (const float*)d_in[3];
    const float* Wk    = (const float*)d_in[4];
    const float* Wkey_ = (const float*)d_in[5];
    const float* u     = (const float*)d_in[6];
    const float* W     = (const float*)d_in[7];
    const float* bb    = (const float*)d_in[8];
    float* out = (float*)d_out;

    float* qws = (float*)d_ws;                  // 131072 f
    float* kws = qws + 131072;                  // 131072 f
    u16* XT = (u16*)(kws + 131072);             // 524288 u16
    u16* Wt = XT + 524288;                      // 262144 u16

    hipLaunchKernelGGL(prep_kernel, dim3(2240), dim3(256), 0, stream,
                       X, Wq, Wk, W, qws, kws, XT, Wt);
    hipLaunchKernelGGL(attn_kernel, dim3(BS * NF * NCH), dim3(256), 0, stream,
                       ac, alpha, Wkey_, u, bb, qws, kws, XT, Wt, out);
}